// Round 5
// baseline (255.358 us; speedup 1.0000x reference)
//
#include <hip/hip_runtime.h>
#include <stdint.h>

// Problem constants (fixed by setup_inputs)
#define B_SZ 2048          // batch
#define D_SZ 2047          // state dim
#define KD   2048          // D+1 == hash_size
#define K_SZ 4096          // input_length (rows of A)
#define TABLE_MASK ((1u << 22) - 1)
#define MARGIN 0.03f       // 3-pass bf16-split worst-case error ~1.3e-2; 2.3x headroom

// old (R3 mid-path) tile constants
#define TJ 128
#define TK 128
#define BK 32

typedef __attribute__((ext_vector_type(8))) short bf16x8;
typedef __attribute__((ext_vector_type(4))) float f32x4;
typedef unsigned short ushort_t;

__device__ __forceinline__ unsigned short f2bf_rn(float x) {
    unsigned int u = __builtin_bit_cast(unsigned int, x);
    unsigned int lsb = (u >> 16) & 1u;
    u += 0x7fffu + lsb;                 // round-to-nearest-even
    return (unsigned short)(u >> 16);
}
__device__ __forceinline__ float bf2f(unsigned short h) {
    unsigned int u = ((unsigned int)h) << 16;
    return __builtin_bit_cast(float, u);
}
__device__ __forceinline__ void gl_lds16(const void* g, void* l) {
    __builtin_amdgcn_global_load_lds(
        (const __attribute__((address_space(1))) unsigned int*)g,
        (__attribute__((address_space(3))) unsigned int*)l, 16, 0, 0);
}

// ===========================================================================
// NEW PATH (ws >= ~85MB): K'=6144 flattened 3-segment GEMM, K-split x2,
// 256 blocks x 512 threads (8 waves, wave-tile 128x64), 3-buffer LDS pipeline
// with counted vmcnt(4), fp32 C partials via atomicAdd (2 adds/elem, exact
// commutative -> deterministic), then sign/hash/defer pass.
// ===========================================================================

// Pass 0: split planes in LDS-image tile layout: per (P panel of 256 rows,
// dt K-tile of 32): elem (r,d) at r*32 + ((d>>3)^(r&3))*8 + (d&7).
__global__ __launch_bounds__(256)
void opiq_split_ks(const float* __restrict__ states,
                   const float* __restrict__ actions,
                   const float* __restrict__ A,
                   ushort_t* __restrict__ Shi, ushort_t* __restrict__ Slo,
                   ushort_t* __restrict__ Ahi, ushort_t* __restrict__ Alo)
{
    const int CS = 524288;                 // S chunks: 2048*2048/8
    const int CT = 1572864;                // + A chunks: 4096*2048/8
    const int i = blockIdx.x * 256 + threadIdx.x;
    if (i >= CT) return;
    const bool isS = (i < CS);
    const int c    = isS ? i : (i - CS);
    const int sp   = c & 3;                // stored 16B slot
    const int r    = (c >> 2) & 255;
    const int tile = c >> 10;              // P*64 + dt
    const int dt   = tile & 63;
    const int P    = tile >> 6;
    const int row  = P * 256 + r;
    const int dbase = dt * 32 + ((sp ^ (r & 3)) << 3);   // inverse swizzle

    float v[8];
    if (isS) {
#pragma unroll
        for (int e = 0; e < 8; ++e) {
            const int d = dbase + e;
            v[e] = (d == D_SZ) ? actions[row] : states[(size_t)row * D_SZ + d];
        }
    } else {
        const float4 a0 = *reinterpret_cast<const float4*>(&A[(size_t)row * KD + dbase]);
        const float4 a1 = *reinterpret_cast<const float4*>(&A[(size_t)row * KD + dbase + 4]);
        v[0]=a0.x; v[1]=a0.y; v[2]=a0.z; v[3]=a0.w;
        v[4]=a1.x; v[5]=a1.y; v[6]=a1.z; v[7]=a1.w;
    }
    bf16x8 hv, lv;
#pragma unroll
    for (int e = 0; e < 8; ++e) {
        const ushort_t h = f2bf_rn(v[e]);
        hv[e] = (short)h;
        lv[e] = (short)f2bf_rn(v[e] - bf2f(h));
    }
    const size_t off = (size_t)c * 8;
    if (isS) { *(bf16x8*)&Shi[off] = hv; *(bf16x8*)&Slo[off] = lv; }
    else     { *(bf16x8*)&Ahi[off] = hv; *(bf16x8*)&Alo[off] = lv; }
}

// Main pipelined GEMM. kt in [kh*96, kh*96+96); seg = kt>>6 selects
// (S-plane, A-plane) in {(sh,ah),(sl,ah),(sh,al)}; dt = kt&63.
__global__ __launch_bounds__(512, 2)
void opiq_gemm_ks(const ushort_t* __restrict__ ShiP, const ushort_t* __restrict__ SloP,
                  const ushort_t* __restrict__ AhiP, const ushort_t* __restrict__ AloP,
                  float* __restrict__ C)
{
    __shared__ __align__(16) ushort_t lds[3][16384];   // 3 x (S 16KB + A 16KB)

    const int tid  = threadIdx.x;
    const int lane = tid & 63;
    const int wid  = tid >> 6;          // 8 waves: 2(M) x 4(N)
    const int wm   = wid >> 2;
    const int wn   = wid & 3;
    const int l15  = lane & 15, lq = lane >> 4;

    // XCD-aware swizzle (256 = 8*32, bijective); kh pairs land on same XCD.
    const int bid = blockIdx.x;
    const int swz = (bid & 7) * 32 + (bid >> 3);
    const int by  = swz >> 5;           // [0,8)  M-tile
    const int bx  = (swz & 31) >> 1;    // [0,16) N-tile
    const int kh  = swz & 1;            // K half
    const int kt0 = kh * 96;

    // frag LDS offsets (ushort units), loop-invariant
    int soff[8], aoff[4];
#pragma unroll
    for (int m = 0; m < 8; ++m) {
        const int row = wm * 128 + m * 16 + l15;
        soff[m] = row * 32 + ((lq ^ (row & 3)) << 3);
    }
#pragma unroll
    for (int n = 0; n < 4; ++n) {
        const int row = wn * 64 + n * 16 + l15;
        aoff[n] = 8192 + row * 32 + ((lq ^ (row & 3)) << 3);
    }

    f32x4 acc[8][4];
#pragma unroll
    for (int m = 0; m < 8; ++m)
#pragma unroll
        for (int n = 0; n < 4; ++n) acc[m][n] = (f32x4){0.f, 0.f, 0.f, 0.f};

    // stage one K-tile (32KB): 4 x gl_lds16 per thread, linear dest
#define STAGE_KT(kt_, stg_)                                                    \
    do {                                                                       \
        const int seg_ = (kt_) >> 6, dt_ = (kt_) & 63;                         \
        const ushort_t* Ss_ = (seg_ == 1 ? SloP : ShiP)                        \
                              + ((size_t)(by * 64 + dt_)) * 8192;              \
        const ushort_t* As_ = (seg_ == 2 ? AloP : AhiP)                        \
                              + ((size_t)(bx * 64 + dt_)) * 8192;              \
        gl_lds16(Ss_ + (size_t)tid * 8,         &lds[stg_][tid * 8]);          \
        gl_lds16(Ss_ + (size_t)(512 + tid) * 8, &lds[stg_][(512 + tid) * 8]);  \
        gl_lds16(As_ + (size_t)tid * 8,         &lds[stg_][8192 + tid * 8]);   \
        gl_lds16(As_ + (size_t)(512 + tid) * 8, &lds[stg_][8192 + (512+tid)*8]);\
    } while (0)

    auto do_tile = [&](const ushort_t* lb) {
        bf16x8 sf[8], af[4];
#pragma unroll
        for (int m = 0; m < 8; ++m) sf[m] = *reinterpret_cast<const bf16x8*>(&lb[soff[m]]);
#pragma unroll
        for (int n = 0; n < 4; ++n) af[n] = *reinterpret_cast<const bf16x8*>(&lb[aoff[n]]);
        __builtin_amdgcn_s_setprio(1);
#pragma unroll
        for (int n = 0; n < 4; ++n)
#pragma unroll
            for (int m = 0; m < 8; ++m)
                acc[m][n] = __builtin_amdgcn_mfma_f32_16x16x32_bf16(sf[m], af[n], acc[m][n], 0, 0, 0);
        __builtin_amdgcn_s_setprio(0);
    };

    // prologue: 2 K-tiles in flight
    STAGE_KT(kt0 + 0, 0);
    STAGE_KT(kt0 + 1, 1);
    asm volatile("s_waitcnt vmcnt(4)" ::: "memory");
    __builtin_amdgcn_s_barrier();
    asm volatile("" ::: "memory");

    int cur = 0, stg = 2;
    for (int t = 0; t < 94; ++t) {
        const ushort_t* lb = lds[cur];
        // issue next-next tile loads; they complete two barriers later
        STAGE_KT(kt0 + t + 2, stg);
        do_tile(lb);
        asm volatile("s_waitcnt vmcnt(4)" ::: "memory");   // t+1's tile ready
        __builtin_amdgcn_s_barrier();
        asm volatile("" ::: "memory");
        cur = (cur == 2) ? 0 : cur + 1;
        stg = (stg == 2) ? 0 : stg + 1;
    }
    // t = 94 (no stage; drain last tile's loads)
    do_tile(lds[cur]);
    asm volatile("s_waitcnt vmcnt(0)" ::: "memory");
    __builtin_amdgcn_s_barrier();
    asm volatile("" ::: "memory");
    cur = (cur == 2) ? 0 : cur + 1;
    // t = 95
    do_tile(lds[cur]);
#undef STAGE_KT

    // epilogue: add partial C tile (exactly 2 adds per element -> deterministic)
    const int j0 = by * 256 + wm * 128;
    const int k0 = bx * 256 + wn * 64;
#pragma unroll
    for (int m = 0; m < 8; ++m) {
#pragma unroll
        for (int r = 0; r < 4; ++r) {
            const int j = j0 + m * 16 + lq * 4 + r;
#pragma unroll
            for (int n = 0; n < 4; ++n) {
                const int k = k0 + n * 16 + l15;
                atomicAdd(&C[(size_t)j * K_SZ + k], acc[m][n][r]);
            }
        }
    }
}

// sign -> weighted hash; borderline -> defer list
__global__ __launch_bounds__(256)
void opiq_signhash(const float* __restrict__ C, const float* __restrict__ bvec,
                   const int* __restrict__ hash_coeffs,
                   unsigned int* __restrict__ hash_acc,
                   unsigned int* __restrict__ defer_cnt,
                   unsigned int* __restrict__ defer_list, unsigned int defer_cap)
{
    const int g  = blockIdx.x * 256 + threadIdx.x;     // < 2048*512
    const int j  = g >> 9;
    const int kb = (g & 511) << 3;
    const float bj = bvec[j];
    const float4 c0 = *reinterpret_cast<const float4*>(&C[(size_t)j * K_SZ + kb]);
    const float4 c1 = *reinterpret_cast<const float4*>(&C[(size_t)j * K_SZ + kb + 4]);
    const float xv[8] = {c0.x, c0.y, c0.z, c0.w, c1.x, c1.y, c1.z, c1.w};
    unsigned int sum = 0;
#pragma unroll
    for (int e = 0; e < 8; ++e) {
        const float x = xv[e] + bj;
        if (__builtin_fabsf(x) <= MARGIN) {
            unsigned int slot = atomicAdd(defer_cnt, 1u);
            if (slot < defer_cap)
                defer_list[slot] = ((unsigned int)j << 12) | (unsigned int)(kb + e);
        } else if (x > 0.0f) {
            sum += (unsigned int)hash_coeffs[kb + e];
        }
    }
#pragma unroll
    for (int m = 1; m < 64; m <<= 1)
        sum += (unsigned int)__shfl_xor((int)sum, m);
    if ((threadIdx.x & 63) == 0) atomicAdd(&hash_acc[j], sum);
}

// ===========================================================================
// MID PATH (ws >= ~54.5MB): R3 kernels verbatim (proven).
// ===========================================================================
__global__ __launch_bounds__(256)
void opiq_split(const float* __restrict__ states,
                const float* __restrict__ actions,
                const float* __restrict__ A,
                ushort_t* __restrict__ Shi, ushort_t* __restrict__ Slo,
                ushort_t* __restrict__ Ahi, ushort_t* __restrict__ Alo)
{
    const long long NS = (long long)B_SZ * KD;
    const long long NA = (long long)K_SZ * KD;
    const long long stride = (long long)gridDim.x * 256;
    for (long long i = (long long)blockIdx.x * 256 + threadIdx.x;
         i < NS + NA; i += stride) {
        float v; int r, d; ushort_t *hi, *lo;
        if (i < NS) {
            r = (int)(i >> 11); d = (int)(i & 2047);
            v = (d == D_SZ) ? actions[r] : states[(size_t)r * D_SZ + d];
            hi = Shi; lo = Slo;
        } else {
            long long ii = i - NS;
            r = (int)(ii >> 11); d = (int)(ii & 2047);
            v = A[(size_t)r * KD + d];
            hi = Ahi; lo = Alo;
        }
        const int key = (r >> 1) & 3;
        const int dd = (d & ~24) | ((((d >> 3) & 3) ^ key) << 3);
        const ushort_t h = f2bf_rn(v);
        const float res = v - bf2f(h);
        const ushort_t l2 = f2bf_rn(res);
        hi[(size_t)r * KD + dd] = h;
        lo[(size_t)r * KD + dd] = l2;
    }
}

__global__ __launch_bounds__(256)
void opiq_gemm_mfma(const ushort_t* __restrict__ Shi, const ushort_t* __restrict__ Slo,
                    const ushort_t* __restrict__ Ahi, const ushort_t* __restrict__ Alo,
                    const float* __restrict__ bvec,
                    const int* __restrict__ hash_coeffs,
                    unsigned int* __restrict__ hash_acc,
                    unsigned int* __restrict__ defer_cnt,
                    unsigned int* __restrict__ defer_list,
                    unsigned int defer_cap)
{
    __shared__ __align__(16) ushort_t lds[2][4][TJ * BK];

    const int tid  = threadIdx.x;
    const int lane = tid & 63;
    const int w    = tid >> 6;
    const int wj   = w >> 1;
    const int wk   = w & 1;

    const int bid = blockIdx.x;
    const int swz = (bid & 7) * 64 + (bid >> 3);
    const int bx = swz & 31;
    const int by = swz >> 5;
    const int j0 = by * TJ;
    const int k0 = bx * TK;

    const ushort_t* gp[4] = { Shi + (size_t)j0 * KD, Slo + (size_t)j0 * KD,
                              Ahi + (size_t)k0 * KD, Alo + (size_t)k0 * KD };
    const int c1 = w * 64 + lane;
    const int c2 = c1 + 256;

    f32x4 acc[4][4];
#pragma unroll
    for (int m = 0; m < 4; ++m)
#pragma unroll
        for (int n = 0; n < 4; ++n) acc[m][n] = (f32x4){0.f, 0.f, 0.f, 0.f};

    const int frow = lane & 15;
    const int key  = (frow >> 1) & 3;
    const int col  = ((lane >> 4) ^ key) * 8;

#define STAGE(buf, t)                                                          \
    do {                                                                       \
        const int d0_ = (t) * BK;                                              \
        _Pragma("unroll")                                                      \
        for (int p_ = 0; p_ < 4; ++p_) {                                       \
            {                                                                  \
                const int row_ = c1 >> 2, cc_ = c1 & 3;                        \
                gl_lds16(gp[p_] + (size_t)row_ * KD + d0_ + cc_ * 8,           \
                         &lds[buf][p_][c1 * 8]);                               \
            }                                                                  \
            {                                                                  \
                const int row_ = c2 >> 2, cc_ = c2 & 3;                        \
                gl_lds16(gp[p_] + (size_t)row_ * KD + d0_ + cc_ * 8,           \
                         &lds[buf][p_][c2 * 8]);                               \
            }                                                                  \
        }                                                                      \
    } while (0)

    STAGE(0, 0);
    __syncthreads();

    for (int t = 0; t < KD / BK; ++t) {
        const int cur = t & 1;
        if (t < KD / BK - 1) STAGE(cur ^ 1, t + 1);

        bf16x8 sh[4], sl[4];
#pragma unroll
        for (int m = 0; m < 4; ++m) {
            sh[m] = *reinterpret_cast<const bf16x8*>(&lds[cur][0][(wj * 64 + m * 16 + frow) * BK + col]);
            sl[m] = *reinterpret_cast<const bf16x8*>(&lds[cur][1][(wj * 64 + m * 16 + frow) * BK + col]);
        }
#pragma unroll
        for (int n = 0; n < 4; ++n) {
            const bf16x8 ah = *reinterpret_cast<const bf16x8*>(&lds[cur][2][(wk * 64 + n * 16 + frow) * BK + col]);
            const bf16x8 al = *reinterpret_cast<const bf16x8*>(&lds[cur][3][(wk * 64 + n * 16 + frow) * BK + col]);
#pragma unroll
            for (int m = 0; m < 4; ++m) {
                acc[m][n] = __builtin_amdgcn_mfma_f32_16x16x32_bf16(sh[m], ah, acc[m][n], 0, 0, 0);
                acc[m][n] = __builtin_amdgcn_mfma_f32_16x16x32_bf16(sh[m], al, acc[m][n], 0, 0, 0);
                acc[m][n] = __builtin_amdgcn_mfma_f32_16x16x32_bf16(sl[m], ah, acc[m][n], 0, 0, 0);
            }
        }
        __syncthreads();
    }
#undef STAGE

#pragma unroll
    for (int m = 0; m < 4; ++m) {
#pragma unroll
        for (int r = 0; r < 4; ++r) {
            const int j = j0 + wj * 64 + m * 16 + (lane >> 4) * 4 + r;
            const float bj = bvec[j];
            unsigned int sum = 0;
#pragma unroll
            for (int n = 0; n < 4; ++n) {
                const int k = k0 + wk * 64 + n * 16 + (lane & 15);
                const float x = acc[m][n][r] + bj;
                if (__builtin_fabsf(x) <= MARGIN) {
                    unsigned int slot = atomicAdd(defer_cnt, 1u);
                    if (slot < defer_cap)
                        defer_list[slot] = ((unsigned int)j << 12) | (unsigned int)k;
                } else if (x > 0.0f) {
                    sum += (unsigned int)hash_coeffs[k];
                }
            }
            sum += (unsigned int)__shfl_xor((int)sum, 1);
            sum += (unsigned int)__shfl_xor((int)sum, 2);
            sum += (unsigned int)__shfl_xor((int)sum, 4);
            sum += (unsigned int)__shfl_xor((int)sum, 8);
            if ((lane & 15) == 0) atomicAdd(&hash_acc[j], sum);
        }
    }
}

// ===========================================================================
// DEEP FALLBACK: exact fp64 (R0), needs only hash_acc.
// ===========================================================================
__global__ __launch_bounds__(256)
void opiq_gemm_f64(const float* __restrict__ states,
                   const float* __restrict__ actions,
                   const float* __restrict__ A,
                   const float* __restrict__ bvec,
                   const int* __restrict__ hash_coeffs,
                   unsigned int* __restrict__ hash_acc)
{
    __shared__ float Slds[64][33];
    __shared__ float Alds[64][33];
    const int tid = threadIdx.x;
    const int tx = tid & 15;
    const int ty = tid >> 4;
    const int j0 = blockIdx.y * 64;
    const int k0 = blockIdx.x * 64;
    double acc[4][4];
#pragma unroll
    for (int i = 0; i < 4; ++i)
#pragma unroll
        for (int jj = 0; jj < 4; ++jj) acc[i][jj] = 0.0;
    for (int d0 = 0; d0 < KD; d0 += 32) {
#pragma unroll
        for (int t = 0; t < 8; ++t) {
            int flat = t * 256 + tid;
            int r = flat >> 5, c = flat & 31;
            int d = d0 + c;
            Slds[r][c] = (d == D_SZ) ? actions[j0 + r] : states[(size_t)(j0 + r) * D_SZ + d];
            Alds[r][c] = A[(size_t)(k0 + r) * KD + d];
        }
        __syncthreads();
#pragma unroll
        for (int dd = 0; dd < 32; ++dd) {
            double s[4], a[4];
#pragma unroll
            for (int i = 0; i < 4; ++i) s[i] = (double)Slds[ty * 4 + i][dd];
#pragma unroll
            for (int jj = 0; jj < 4; ++jj) a[jj] = (double)Alds[tx * 4 + jj][dd];
#pragma unroll
            for (int i = 0; i < 4; ++i)
#pragma unroll
                for (int jj = 0; jj < 4; ++jj)
                    acc[i][jj] = fma(s[i], a[jj], acc[i][jj]);
        }
        __syncthreads();
    }
#pragma unroll
    for (int i = 0; i < 4; ++i) {
        const int j = j0 + ty * 4 + i;
        const double bj = (double)bvec[j];
        unsigned int sum = 0;
#pragma unroll
        for (int jj = 0; jj < 4; ++jj) {
            const int k = k0 + tx * 4 + jj;
            if (acc[i][jj] + bj > 0.0) sum += (unsigned int)hash_coeffs[k];
        }
        sum += (unsigned int)__shfl_xor((int)sum, 1);
        sum += (unsigned int)__shfl_xor((int)sum, 2);
        sum += (unsigned int)__shfl_xor((int)sum, 4);
        sum += (unsigned int)__shfl_xor((int)sum, 8);
        if (tx == 0) atomicAdd(&hash_acc[j], sum);
    }
}

// Exact fp64 recompute of deferred dots; one wave per deferred (j,k) pair.
__global__ __launch_bounds__(256)
void opiq_fixup(const float* __restrict__ states,
                const float* __restrict__ actions,
                const float* __restrict__ A,
                const float* __restrict__ bvec,
                const int* __restrict__ hash_coeffs,
                unsigned int* __restrict__ hash_acc,
                const unsigned int* __restrict__ defer_cnt,
                const unsigned int* __restrict__ defer_list,
                unsigned int defer_cap)
{
    const int gtid = blockIdx.x * 256 + threadIdx.x;
    const int wave = gtid >> 6;
    const int lane = gtid & 63;
    const int n_waves = gridDim.x * 4;

    unsigned int n = *defer_cnt;
    if (n > defer_cap) n = defer_cap;

    for (unsigned int e = wave; e < n; e += n_waves) {
        const unsigned int ent = defer_list[e];
        const int j = (int)(ent >> 12);
        const int k = (int)(ent & 4095);
        double part = 0.0;
        const int dbase = lane * 32;
#pragma unroll 8
        for (int t = 0; t < 32; ++t) {
            const int d = dbase + t;
            const float sv = (d == D_SZ) ? actions[j]
                                         : states[(size_t)j * D_SZ + d];
            part = fma((double)sv, (double)A[(size_t)k * KD + d], part);
        }
#pragma unroll
        for (int m = 1; m < 64; m <<= 1)
            part += __shfl_xor(part, m);
        const double x = part + (double)bvec[j];
        if (lane == 0 && x > 0.0)
            atomicAdd(&hash_acc[j], (unsigned int)hash_coeffs[k]);
    }
}

__global__ void opiq_final(const unsigned int* __restrict__ hash_acc,
                           const int* __restrict__ count_table,
                           float* __restrict__ out)
{
    int j = blockIdx.x * 256 + threadIdx.x;
    if (j < B_SZ) {
        unsigned int idx = hash_acc[j] & TABLE_MASK;
        float c = (float)count_table[idx];
        float t = c + 1.0f;
        out[j] = 1.0f / (t * t);
    }
}

extern "C" void kernel_launch(void* const* d_in, const int* in_sizes, int n_in,
                              void* d_out, int out_size, void* d_ws, size_t ws_size,
                              hipStream_t stream) {
    const float* states      = (const float*)d_in[0];
    const float* actions     = (const float*)d_in[1];
    const float* A           = (const float*)d_in[2];
    const float* bvec        = (const float*)d_in[3];
    const int*   count_table = (const int*)d_in[4];
    const int*   hash_coeffs = (const int*)d_in[5];
    float* out = (float*)d_out;

    unsigned int* hash_acc  = (unsigned int*)d_ws;
    unsigned int* defer_cnt = hash_acc + B_SZ;

    // --- NEW path layout ---
    const size_t DEFER_OFF_N  = 16384;
    const size_t DEFER_CAP_N  = 262144;                         // 1MB
    const size_t C_OFF        = DEFER_OFF_N + DEFER_CAP_N * 4;  // 1,064,960
    const size_t C_BYTES      = (size_t)B_SZ * K_SZ * 4;        // 33.5MB
    const size_t PLANES_OFF_N = C_OFF + C_BYTES;
    const size_t S_ELEMS = (size_t)B_SZ * KD;                   // 4.19M
    const size_t A_ELEMS = (size_t)K_SZ * KD;                   // 8.39M
    const size_t REQ_NEW = PLANES_OFF_N + 2 * (S_ELEMS + A_ELEMS) * 2;

    // --- MID (R3) layout ---
    const size_t DEFER_OFF_M  = 16384;
    const size_t DEFER_CAP_M  = 1u << 20;
    const size_t PLANES_OFF_M = DEFER_OFF_M + DEFER_CAP_M * 4;
    const size_t REQ_MID = PLANES_OFF_M + 2 * (S_ELEMS + A_ELEMS) * 2;

    if (ws_size >= REQ_NEW) {
        unsigned int* defer_list = (unsigned int*)((char*)d_ws + DEFER_OFF_N);
        float*    C   = (float*)((char*)d_ws + C_OFF);
        ushort_t* Shi = (ushort_t*)((char*)d_ws + PLANES_OFF_N);
        ushort_t* Slo = Shi + S_ELEMS;
        ushort_t* Ahi = Slo + S_ELEMS;
        ushort_t* Alo = Ahi + A_ELEMS;

        hipMemsetAsync(d_ws, 0, DEFER_OFF_N, stream);
        hipMemsetAsync(C, 0, C_BYTES, stream);
        opiq_split_ks<<<6144, 256, 0, stream>>>(states, actions, A, Shi, Slo, Ahi, Alo);
        opiq_gemm_ks<<<256, 512, 0, stream>>>(Shi, Slo, Ahi, Alo, C);
        opiq_signhash<<<4096, 256, 0, stream>>>(C, bvec, hash_coeffs, hash_acc,
                                                defer_cnt, defer_list,
                                                (unsigned int)DEFER_CAP_N);
        opiq_fixup<<<128, 256, 0, stream>>>(states, actions, A, bvec, hash_coeffs,
                                            hash_acc, defer_cnt, defer_list,
                                            (unsigned int)DEFER_CAP_N);
    } else if (ws_size >= REQ_MID) {
        unsigned int* defer_list = (unsigned int*)((char*)d_ws + DEFER_OFF_M);
        ushort_t* Shi = (ushort_t*)((char*)d_ws + PLANES_OFF_M);
        ushort_t* Slo = Shi + S_ELEMS;
        ushort_t* Ahi = Slo + S_ELEMS;
        ushort_t* Alo = Ahi + A_ELEMS;

        hipMemsetAsync(d_ws, 0, DEFER_OFF_M, stream);
        opiq_split<<<4096, 256, 0, stream>>>(states, actions, A, Shi, Slo, Ahi, Alo);
        opiq_gemm_mfma<<<512, 256, 0, stream>>>(Shi, Slo, Ahi, Alo, bvec,
                                                hash_coeffs, hash_acc,
                                                defer_cnt, defer_list,
                                                (unsigned int)DEFER_CAP_M);
        opiq_fixup<<<128, 256, 0, stream>>>(states, actions, A, bvec, hash_coeffs,
                                            hash_acc, defer_cnt, defer_list,
                                            (unsigned int)DEFER_CAP_M);
    } else {
        hipMemsetAsync(d_ws, 0, B_SZ * sizeof(unsigned int), stream);
        dim3 grid(K_SZ / 64, B_SZ / 64);
        opiq_gemm_f64<<<grid, 256, 0, stream>>>(states, actions, A, bvec,
                                                hash_coeffs, hash_acc);
    }
    opiq_final<<<(B_SZ + 255) / 256, 256, 0, stream>>>(hash_acc, count_table, out);
}